// Round 3
// baseline (169.539 us; speedup 1.0000x reference)
//
#include <hip/hip_runtime.h>
#include <math.h>

// GCN 2-layer. R12: CSR restructure. k_bin buckets edges (1 LDS atomic/edge);
// k_degP counts per-(node,sub) (1 LDS op/edge; counts double as degrees and
// sort keys); k_scan prefix-sums each bucket -> run starts, dinv, xs; k_place
// counting-sorts each bucket by local node id (1 LDS atomic/edge, cnt[] is
// pre-seeded with run starts so the atomic's return IS the position); then
// agg1/agg2 are ATOMIC-FREE: 8 lanes per node walk the contiguous run,
// register-accumulate fp32, shfl_xor reduce, fused MLP/sigmoid epilogue.
// Kills agg1P/agg2P LDS-atomic scatters (~85us in R10 decomposition) and all
// u64 fixed-point partial traffic. Predict ~115-125us.

#define NPB 256        // nodes per bucket (power of 2)
#define SHIFT 8        // log2(NPB)
#define NB_MAX 512     // max buckets supported by LDS arrays in k_bin
#define SPLIT 8        // sub-blocks per bucket in partial kernels
#define T1 512         // threads per block in k_bin
#define EPT 16         // edges staged per thread in k_bin (tile = 8192 edges)

#define FSCALE 1024.0f     // fixed-point scale (2^10)  [mid-tier fallback only]
#define FBIAS  8192        // per-addend bias (2^13)
#define FMASK  0x1FFFFFu   // 21-bit field mask

static __device__ __forceinline__ long long load_idx(const void* edges, long long pos, int is64) {
    if (is64) return ((const long long*)edges)[pos];
    return (long long)((const int*)edges)[pos];
}

static __device__ __forceinline__ unsigned long long pack3(float x, float y, float z) {
    unsigned long long e0 = (unsigned)(__float2int_rn(x * FSCALE) + FBIAS);
    unsigned long long e1 = (unsigned)(__float2int_rn(y * FSCALE) + FBIAS);
    unsigned long long e2 = (unsigned)(__float2int_rn(z * FSCALE) + FBIAS);
    return e0 | (e1 << 21) | (e2 << 42);
}

// zero cursors + dtype-detect flag (merged)
__global__ void k_zero_cursor(int* cursor, int nb, const int* e32, int* flag) {
    int i = blockIdx.x * blockDim.x + threadIdx.x;
    if (i < nb) cursor[i] = 0;
    if (i == 0) {
        int is64 = 1;
        for (int k = 0; k < 16; ++k)
            if (e32[2 * k + 1] != 0) { is64 = 0; break; }
        *flag = is64;
    }
}

// Register-staged binning: ONE pass over the edge list; 1 LDS atomic/edge
// (the histogram atomic's return value doubles as the placement rank).
__global__ void k_bin(const void* edges, const int* __restrict__ flag,
                      int* __restrict__ cursor, unsigned int* __restrict__ bin,
                      long long E, int nb, int cap) {
    __shared__ int hist[NB_MAX];
    __shared__ int base[NB_MAX];
    const int tid = threadIdx.x;
    for (int b = tid; b < nb; b += T1) hist[b] = 0;
    __syncthreads();

    const int is64 = *flag;
    const long long start = (long long)blockIdx.x * ((long long)T1 * EPT);
    unsigned es[EPT], ed[EPT];
    int rank[EPT];

    if (is64) {
        const long long* e64 = (const long long*)edges;
#pragma unroll
        for (int j = 0; j < EPT; ++j) {
            long long e = start + j * T1 + tid;
            if (e < E) { es[j] = (unsigned)e64[e]; ed[j] = (unsigned)e64[E + e]; }
            else ed[j] = 0xFFFFFFFFu;
        }
    } else {
        const int* e32 = (const int*)edges;
#pragma unroll
        for (int j = 0; j < EPT; ++j) {
            long long e = start + j * T1 + tid;
            if (e < E) { es[j] = (unsigned)e32[e]; ed[j] = (unsigned)e32[E + e]; }
            else ed[j] = 0xFFFFFFFFu;
        }
    }

#pragma unroll
    for (int j = 0; j < EPT; ++j)
        if (ed[j] != 0xFFFFFFFFu)
            rank[j] = atomicAdd(&hist[ed[j] >> SHIFT], 1);
    __syncthreads();

    for (int b = tid; b < nb; b += T1) {
        int h = hist[b];
        base[b] = h ? atomicAdd(&cursor[b], h) : 0;
    }
    __syncthreads();

#pragma unroll
    for (int j = 0; j < EPT; ++j) {
        if (ed[j] == 0xFFFFFFFFu) continue;
        int bk = (int)(ed[j] >> SHIFT);
        int off = base[bk] + rank[j];
        if (off < cap)
            bin[(long long)bk * cap + off] = ((ed[j] & (NPB - 1)) << 17) | es[j];
    }
}

static __device__ __forceinline__ void sub_range(int cnt, int sub, int* lo, int* hi) {
    int l = (int)(((long long)cnt * sub / SPLIT) & ~3LL);
    int h = (sub == SPLIT - 1) ? cnt : (int)(((long long)cnt * (sub + 1) / SPLIT) & ~3LL);
    *lo = l; *hi = h;
}

// ---- degree partial counts (doubles as counting-sort key pass) ----
__global__ void k_degP(const unsigned int* __restrict__ bin, const int* __restrict__ cursor,
                       int* __restrict__ part, int cap) {
    __shared__ int dcnt[NPB];
    const int tid = threadIdx.x;
    dcnt[tid] = 0;
    __syncthreads();
    const int bk = blockIdx.x >> 3;
    const int sub = blockIdx.x & (SPLIT - 1);
    const int cnt = min(cursor[bk], cap);
    int lo, hi; sub_range(cnt, sub, &lo, &hi);
    const unsigned int* bp = bin + (long long)bk * cap;
    const int len = hi - lo, nvec = len >> 2;
    const uint4* bp4 = (const uint4*)(bp + lo);
    for (int v = tid; v < nvec; v += NPB) {
        uint4 q = bp4[v];
        atomicAdd(&dcnt[q.x >> 17], 1);
        atomicAdd(&dcnt[q.y >> 17], 1);
        atomicAdd(&dcnt[q.z >> 17], 1);
        atomicAdd(&dcnt[q.w >> 17], 1);
    }
    for (int k = lo + (nvec << 2) + tid; k < hi; k += NPB)
        atomicAdd(&dcnt[bp[k] >> 17], 1);
    __syncthreads();
    part[(long long)blockIdx.x * NPB + tid] = dcnt[tid];
}

// ---- NEW: per-bucket prefix scan -> run starts, dinv, pre-scaled xs ----
__global__ void k_scan(const int* __restrict__ part, const float* __restrict__ x,
                       float* __restrict__ dinv, float4* __restrict__ xs,
                       unsigned int* __restrict__ subStart, unsigned int* __restrict__ startAbs,
                       int n, int cap) {
    __shared__ int sc[NPB];
    const int lid = threadIdx.x;
    const int bk = blockIdx.x;
    const int i = bk * NPB + lid;
    int subOff[SPLIT];
    int degE = 0;
#pragma unroll
    for (int s = 0; s < SPLIT; ++s) {
        subOff[s] = degE;
        degE += part[(long long)(bk * SPLIT + s) * NPB + lid];
    }
    sc[lid] = degE;
    __syncthreads();
    // inclusive Hillis-Steele scan over the bucket's 256 nodes
    for (int off = 1; off < NPB; off <<= 1) {
        int v = (lid >= off) ? sc[lid - off] : 0;
        __syncthreads();
        sc[lid] += v;
        __syncthreads();
    }
    unsigned base = (unsigned)bk * (unsigned)cap + (unsigned)(sc[lid] - degE); // exclusive
#pragma unroll
    for (int s = 0; s < SPLIT; ++s)
        subStart[(long long)(bk * SPLIT + s) * NPB + lid] = base + (unsigned)subOff[s];
    if (i < n) {
        startAbs[i] = base;
        float di = rsqrtf((float)degE + 1.0f);
        dinv[i] = di;
        xs[i] = make_float4(x[3 * i] * di, x[3 * i + 1] * di, x[3 * i + 2] * di, (float)degE);
    }
}

// ---- NEW: counting-sort placement; cnt[] seeded with run starts so the
// rank atomic's return value IS the final bin2 position. 1 LDS atomic/edge.
__global__ void k_place(const unsigned int* __restrict__ bin, const int* __restrict__ cursor,
                        const unsigned int* __restrict__ subStart,
                        unsigned int* __restrict__ bin2, int cap) {
    __shared__ unsigned int cnt[NPB];
    const int tid = threadIdx.x;
    cnt[tid] = subStart[(long long)blockIdx.x * NPB + tid];
    __syncthreads();
    const int bk = blockIdx.x >> 3;
    const int sub = blockIdx.x & (SPLIT - 1);
    const int cnt_b = min(cursor[bk], cap);
    int lo, hi; sub_range(cnt_b, sub, &lo, &hi);
    const unsigned int* bp = bin + (long long)bk * cap;
    const int len = hi - lo, nvec = len >> 2;
    const uint4* bp4 = (const uint4*)(bp + lo);
    for (int v = tid; v < nvec; v += NPB) {
        uint4 q = bp4[v];
        unsigned p0 = atomicAdd(&cnt[q.x >> 17], 1u);
        unsigned p1 = atomicAdd(&cnt[q.y >> 17], 1u);
        unsigned p2 = atomicAdd(&cnt[q.z >> 17], 1u);
        unsigned p3 = atomicAdd(&cnt[q.w >> 17], 1u);
        bin2[p0] = q.x & 0x1FFFFu;
        bin2[p1] = q.y & 0x1FFFFu;
        bin2[p2] = q.z & 0x1FFFFu;
        bin2[p3] = q.w & 0x1FFFFu;
    }
    for (int k = lo + (nvec << 2) + tid; k < hi; k += NPB) {
        unsigned q = bp[k];
        unsigned p = atomicAdd(&cnt[q >> 17], 1u);
        bin2[p] = q & 0x1FFFFu;
    }
}

// ---- NEW: layer 1, atomic-free. 8 lanes/node walk the CSR run, register
// accumulate, shfl_xor reduce, fused MLP -> gs. ----
__global__ void k_agg1F(const unsigned int* __restrict__ bin2,
                        const unsigned int* __restrict__ startAbs,
                        const float4* __restrict__ xs, const float* __restrict__ dinv,
                        const float* __restrict__ W1, const float* __restrict__ b1,
                        const float* __restrict__ W2, float* __restrict__ gs, int n) {
    const int tid = threadIdx.x;                     // 256
    const int bk = blockIdx.x >> 3;
    const int sub = blockIdx.x & 7;
    const int g = tid >> 3, l = tid & 7;             // 32 nodes x 8 lanes
    const int i = bk * NPB + sub * 32 + g;
    if (i >= n) return;
    const unsigned start = startAbs[i];
    const float4 self = xs[i];
    const int degE = (int)self.w;
    float a0 = 0.f, a1 = 0.f, a2 = 0.f;
    for (int k = l; k < degE; k += 8) {
        unsigned src = bin2[start + k];
        float4 v = xs[src];
        a0 += v.x; a1 += v.y; a2 += v.z;
    }
#pragma unroll
    for (int m = 1; m < 8; m <<= 1) {
        a0 += __shfl_xor(a0, m);
        a1 += __shfl_xor(a1, m);
        a2 += __shfl_xor(a2, m);
    }
    float di = dinv[i];
    a0 = (a0 + self.x) * di; a1 = (a1 + self.y) * di; a2 = (a2 + self.z) * di;
    float gsum = 0.f;
#pragma unroll
    for (int c = 0; c < 16; ++c) {   // W1 [3,16] row-major
        float h = fmaf(a0, W1[c], fmaf(a1, W1[16 + c], fmaf(a2, W1[32 + c], b1[c])));
        h = fmaxf(h, 0.0f);
        gsum = fmaf(h, W2[c], gsum);
    }
    if (l == 0) gs[i] = gsum * di;   // pre-scaled by dinv for layer-2 src side
}

// ---- NEW: layer 2, atomic-free, fused sigmoid epilogue. ----
__global__ void k_agg2F(const unsigned int* __restrict__ bin2,
                        const unsigned int* __restrict__ startAbs,
                        const float4* __restrict__ xs, const float* __restrict__ gs,
                        const float* __restrict__ dinv, const float* __restrict__ b2,
                        float* __restrict__ out, int n) {
    const int tid = threadIdx.x;
    const int bk = blockIdx.x >> 3;
    const int sub = blockIdx.x & 7;
    const int g = tid >> 3, l = tid & 7;
    const int i = bk * NPB + sub * 32 + g;
    if (i >= n) return;
    const unsigned start = startAbs[i];
    const int degE = (int)xs[i].w;
    float acc = 0.f;
    for (int k = l; k < degE; k += 8)
        acc += gs[bin2[start + k]];
#pragma unroll
    for (int m = 1; m < 8; m <<= 1)
        acc += __shfl_xor(acc, m);
    if (l == 0) {
        float z = dinv[i] * (acc + gs[i]) + b2[0];
        out[i] = 1.0f / (1.0f + expf(-z));
    }
}

// ---------------- R11 mid-tier (proven 156us) ----------------
__global__ void k_degC(const int* __restrict__ part, const float* __restrict__ x,
                       float* __restrict__ dinv, float4* __restrict__ xs, int n) {
    const int tid = threadIdx.x;
    const int bk = blockIdx.x;
    const int i = bk * NPB + tid;
    if (i >= n) return;
    int degE = 0;
#pragma unroll
    for (int s = 0; s < SPLIT; ++s)
        degE += part[(long long)(bk * SPLIT + s) * NPB + tid];
    float di = rsqrtf((float)degE + 1.0f);
    dinv[i] = di;
    xs[i] = make_float4(x[3 * i] * di, x[3 * i + 1] * di, x[3 * i + 2] * di, (float)degE);
}

__global__ void k_agg1P(const unsigned int* __restrict__ bin, const int* __restrict__ cursor,
                        const float4* __restrict__ xs, unsigned long long* __restrict__ part,
                        int cap) {
    __shared__ unsigned long long acc[NPB];
    const int tid = threadIdx.x;
    acc[tid] = 0ull;
    __syncthreads();
    const int bk = blockIdx.x >> 3;
    const int sub = blockIdx.x & (SPLIT - 1);
    const int cnt = min(cursor[bk], cap);
    int lo, hi; sub_range(cnt, sub, &lo, &hi);
    const unsigned int* bp = bin + (long long)bk * cap;
    const int len = hi - lo, nvec = len >> 2;
    const uint4* bp4 = (const uint4*)(bp + lo);
    for (int v = tid; v < nvec; v += NPB) {
        uint4 q = bp4[v];
        float4 v0 = xs[q.x & 0x1FFFFu];
        float4 v1 = xs[q.y & 0x1FFFFu];
        float4 v2 = xs[q.z & 0x1FFFFu];
        float4 v3 = xs[q.w & 0x1FFFFu];
        atomicAdd(&acc[q.x >> 17], pack3(v0.x, v0.y, v0.z));
        atomicAdd(&acc[q.y >> 17], pack3(v1.x, v1.y, v1.z));
        atomicAdd(&acc[q.z >> 17], pack3(v2.x, v2.y, v2.z));
        atomicAdd(&acc[q.w >> 17], pack3(v3.x, v3.y, v3.z));
    }
    for (int k = lo + (nvec << 2) + tid; k < hi; k += NPB) {
        unsigned p = bp[k];
        float4 v = xs[p & 0x1FFFFu];
        atomicAdd(&acc[p >> 17], pack3(v.x, v.y, v.z));
    }
    __syncthreads();
    part[(long long)blockIdx.x * NPB + tid] = acc[tid];
}

__global__ void k_agg1C(const unsigned long long* __restrict__ part,
                        const float* __restrict__ dinv, const float4* __restrict__ xs,
                        const float* __restrict__ W1, const float* __restrict__ b1,
                        const float* __restrict__ W2, float* __restrict__ gs, int n) {
    const int tid = threadIdx.x;
    const int bk = blockIdx.x;
    const int i = bk * NPB + tid;
    if (i >= n) return;
    int f0 = 0, f1 = 0, f2 = 0;
#pragma unroll
    for (int s = 0; s < SPLIT; ++s) {
        unsigned long long p = part[(long long)(bk * SPLIT + s) * NPB + tid];
        f0 += (int)(p & FMASK);
        f1 += (int)((p >> 21) & FMASK);
        f2 += (int)((p >> 42) & FMASK);
    }
    float4 self = xs[i];
    int degE = (int)self.w;
    const float inv = 1.0f / FSCALE;
    float a0 = (float)(f0 - FBIAS * degE) * inv + self.x;
    float a1 = (float)(f1 - FBIAS * degE) * inv + self.y;
    float a2 = (float)(f2 - FBIAS * degE) * inv + self.z;
    float di = dinv[i];
    a0 *= di; a1 *= di; a2 *= di;
    float g = 0.0f;
#pragma unroll
    for (int c = 0; c < 16; ++c) {
        float h = fmaf(a0, W1[c], fmaf(a1, W1[16 + c], fmaf(a2, W1[32 + c], b1[c])));
        h = fmaxf(h, 0.0f);
        g = fmaf(h, W2[c], g);
    }
    gs[i] = g * di;
}

__global__ void k_agg2P(const unsigned int* __restrict__ bin, const int* __restrict__ cursor,
                        const float* __restrict__ gs, float* __restrict__ part, int cap) {
    __shared__ float acc[NPB];
    const int tid = threadIdx.x;
    acc[tid] = 0.0f;
    __syncthreads();
    const int bk = blockIdx.x >> 3;
    const int sub = blockIdx.x & (SPLIT - 1);
    const int cnt = min(cursor[bk], cap);
    int lo, hi; sub_range(cnt, sub, &lo, &hi);
    const unsigned int* bp = bin + (long long)bk * cap;
    const int len = hi - lo, nvec = len >> 2;
    const uint4* bp4 = (const uint4*)(bp + lo);
    for (int v = tid; v < nvec; v += NPB) {
        uint4 q = bp4[v];
        float g0 = gs[q.x & 0x1FFFFu];
        float g1 = gs[q.y & 0x1FFFFu];
        float g2 = gs[q.z & 0x1FFFFu];
        float g3 = gs[q.w & 0x1FFFFu];
        atomicAdd(&acc[q.x >> 17], g0);
        atomicAdd(&acc[q.y >> 17], g1);
        atomicAdd(&acc[q.z >> 17], g2);
        atomicAdd(&acc[q.w >> 17], g3);
    }
    for (int k = lo + (nvec << 2) + tid; k < hi; k += NPB) {
        unsigned p = bp[k];
        atomicAdd(&acc[p >> 17], gs[p & 0x1FFFFu]);
    }
    __syncthreads();
    part[(long long)blockIdx.x * NPB + tid] = acc[tid];
}

__global__ void k_agg2C(const float* __restrict__ part, const float* __restrict__ dinv,
                        const float* __restrict__ gs, const float* __restrict__ b2,
                        float* __restrict__ out, int n) {
    const int tid = threadIdx.x;
    const int bk = blockIdx.x;
    const int i = bk * NPB + tid;
    if (i >= n) return;
    float acc = gs[i];
#pragma unroll
    for (int s = 0; s < SPLIT; ++s)
        acc += part[(long long)(bk * SPLIT + s) * NPB + tid];
    float z = dinv[i] * acc + b2[0];
    out[i] = 1.0f / (1.0f + expf(-z));
}

// ---------------- R1 fallback (small ws) ----------------
__global__ void k_detect(const int* e32, int* flag) {
    if (blockIdx.x == 0 && threadIdx.x == 0) {
        int is64 = 1;
        for (int k = 0; k < 16; ++k)
            if (e32[2 * k + 1] != 0) { is64 = 0; break; }
        *flag = is64;
    }
}
__global__ void f_init_deg(float* deg, int n) {
    int i = blockIdx.x * blockDim.x + threadIdx.x;
    if (i < n) deg[i] = 1.0f;
}
__global__ void f_deg(const void* edges, const int* flag, float* deg, long long E) {
    int is64 = *flag;
    long long e = (long long)blockIdx.x * blockDim.x + threadIdx.x;
    if (e < E) atomicAdd(&deg[load_idx(edges, E + e, is64)], 1.0f);
}
__global__ void f_dinv_xs(const float* x, const float* deg, float* dinv, float4* xs,
                          float4* agg3, int n) {
    int i = blockIdx.x * blockDim.x + threadIdx.x;
    if (i < n) {
        float di = rsqrtf(deg[i]);
        dinv[i] = di;
        float4 v = make_float4(x[3 * i] * di, x[3 * i + 1] * di, x[3 * i + 2] * di, 0.0f);
        xs[i] = v; agg3[i] = v;
    }
}
__global__ void f_edge1(const void* edges, const int* flag, const float4* xs,
                        float* agg3, long long E) {
    int is64 = *flag;
    long long e = (long long)blockIdx.x * blockDim.x + threadIdx.x;
    if (e < E) {
        long long s = load_idx(edges, e, is64);
        long long d = load_idx(edges, E + e, is64);
        float4 v = xs[s];
        atomicAdd(&agg3[4 * d + 0], v.x);
        atomicAdd(&agg3[4 * d + 1], v.y);
        atomicAdd(&agg3[4 * d + 2], v.z);
    }
}
__global__ void f_node1(const float* dinv, const float4* agg3, const float* W1,
                        const float* b1, const float* W2, float* gs, float* agg1, int n) {
    int i = blockIdx.x * blockDim.x + threadIdx.x;
    if (i < n) {
        float di = dinv[i];
        float4 a = agg3[i];
        float a0 = a.x * di, a1 = a.y * di, a2 = a.z * di;
        float g = 0.0f;
#pragma unroll
        for (int k = 0; k < 16; ++k) {
            float h = fmaf(a0, W1[k], fmaf(a1, W1[16 + k], fmaf(a2, W1[32 + k], b1[k])));
            h = fmaxf(h, 0.0f);
            g = fmaf(h, W2[k], g);
        }
        float v = g * di;
        gs[i] = v; agg1[i] = v;
    }
}
__global__ void f_edge2(const void* edges, const int* flag, const float* gs,
                        float* agg1, long long E) {
    int is64 = *flag;
    long long e = (long long)blockIdx.x * blockDim.x + threadIdx.x;
    if (e < E) atomicAdd(&agg1[load_idx(edges, E + e, is64)], gs[load_idx(edges, e, is64)]);
}
__global__ void f_final(const float* dinv, const float* agg1, const float* b2,
                        float* out, int n) {
    int i = blockIdx.x * blockDim.x + threadIdx.x;
    if (i < n) {
        float z = dinv[i] * agg1[i] + b2[0];
        out[i] = 1.0f / (1.0f + expf(-z));
    }
}

extern "C" void kernel_launch(void* const* d_in, const int* in_sizes, int n_in,
                              void* d_out, int out_size, void* d_ws, size_t ws_size,
                              hipStream_t stream) {
    const float* x  = (const float*)d_in[0];
    const void*  ei = d_in[1];
    const float* W1 = (const float*)d_in[2];
    const float* b1 = (const float*)d_in[3];
    const float* W2 = (const float*)d_in[4];
    const float* b2 = (const float*)d_in[5];
    float* out = (float*)d_out;

    const long long n = in_sizes[0] / 3;   // 100000
    const long long E = in_sizes[1] / 2;   // 3200000

    const int T = 256;
    const int gN = (int)((n + T - 1) / T);
    const int gE = (int)((E + T - 1) / T);

    const int nb = (int)((n + NPB - 1) / NPB);                       // 391
    long long capll = (E / nb) + (E / nb) / 8 + 256;                 // mean + ~11 sigma
    const int cap = (int)((capll + 63) / 64 * 64);

    // New CSR path workspace
    size_t needNew = n * sizeof(float4)                              // xs
                   + (size_t)nb * SPLIT * NPB * sizeof(int)          // counts
                   + (size_t)nb * SPLIT * NPB * sizeof(int)          // subStart
                   + (size_t)nb * cap * sizeof(int)                  // bin
                   + (size_t)nb * cap * sizeof(int)                  // bin2
                   + 3 * n * sizeof(float)                           // dinv, gs, startAbs
                   + nb * sizeof(int) + 128;                         // cursor, flag
    // R11 mid-tier workspace
    size_t needMid = n * sizeof(float4)
                   + (size_t)nb * SPLIT * NPB * sizeof(float4)
                   + (size_t)nb * cap * sizeof(int)
                   + 2 * n * sizeof(float)
                   + nb * sizeof(int) + 128;

    if (nb <= NB_MAX && n <= (1 << 17) && ws_size >= needNew) {
        char* p = (char*)d_ws;
        float4* xs   = (float4*)p;            p += n * sizeof(float4);
        int* cnts    = (int*)p;               p += (size_t)nb * SPLIT * NPB * sizeof(int);
        unsigned int* subStart = (unsigned int*)p; p += (size_t)nb * SPLIT * NPB * sizeof(int);
        unsigned int* bin  = (unsigned int*)p; p += (size_t)nb * cap * sizeof(int);
        unsigned int* bin2 = (unsigned int*)p; p += (size_t)nb * cap * sizeof(int);
        float* dinv  = (float*)p;             p += n * sizeof(float);
        float* gs    = (float*)p;             p += n * sizeof(float);
        unsigned int* startAbs = (unsigned int*)p; p += n * sizeof(int);
        int*   cursor = (int*)p;              p += nb * sizeof(int);
        int*   flag  = (int*)p;

        const long long per_blk = (long long)T1 * EPT;               // 8192 edges/block
        const int gB = (int)((E + per_blk - 1) / per_blk);           // 391

        k_zero_cursor<<<(nb + T - 1) / T, T, 0, stream>>>(cursor, nb, (const int*)ei, flag);
        k_bin<<<gB, T1, 0, stream>>>(ei, flag, cursor, bin, E, nb, cap);
        k_degP<<<nb * SPLIT, NPB, 0, stream>>>(bin, cursor, cnts, cap);
        k_scan<<<nb, NPB, 0, stream>>>(cnts, x, dinv, xs, subStart, startAbs, (int)n, cap);
        k_place<<<nb * SPLIT, NPB, 0, stream>>>(bin, cursor, subStart, bin2, cap);
        k_agg1F<<<nb * SPLIT, NPB, 0, stream>>>(bin2, startAbs, xs, dinv, W1, b1, W2, gs, (int)n);
        k_agg2F<<<nb * SPLIT, NPB, 0, stream>>>(bin2, startAbs, xs, gs, dinv, b2, out, (int)n);
    } else if (nb <= NB_MAX && n <= (1 << 17) && ws_size >= needMid) {
        // R11 proven pipeline (156us)
        char* p = (char*)d_ws;
        float4* xs   = (float4*)p;       p += n * sizeof(float4);
        char*  partb = p;                p += (size_t)nb * SPLIT * NPB * sizeof(float4);
        unsigned int* bin = (unsigned int*)p; p += (size_t)nb * cap * sizeof(int);
        float* dinv  = (float*)p;        p += n * sizeof(float);
        float* gs    = (float*)p;        p += n * sizeof(float);
        int*   cursor = (int*)p;         p += nb * sizeof(int);
        int*   flag  = (int*)p;

        const long long per_blk = (long long)T1 * EPT;
        const int gB = (int)((E + per_blk - 1) / per_blk);

        k_zero_cursor<<<(nb + T - 1) / T, T, 0, stream>>>(cursor, nb, (const int*)ei, flag);
        k_bin<<<gB, T1, 0, stream>>>(ei, flag, cursor, bin, E, nb, cap);
        k_degP<<<nb * SPLIT, NPB, 0, stream>>>(bin, cursor, (int*)partb, cap);
        k_degC<<<nb, NPB, 0, stream>>>((const int*)partb, x, dinv, xs, (int)n);
        k_agg1P<<<nb * SPLIT, NPB, 0, stream>>>(bin, cursor, xs, (unsigned long long*)partb, cap);
        k_agg1C<<<nb, NPB, 0, stream>>>((const unsigned long long*)partb, dinv, xs, W1, b1, W2, gs, (int)n);
        k_agg2P<<<nb * SPLIT, NPB, 0, stream>>>(bin, cursor, gs, (float*)partb, cap);
        k_agg2C<<<nb, NPB, 0, stream>>>((const float*)partb, dinv, gs, b2, out, (int)n);
    } else {
        // R1 proven atomic pipeline
        char* p = (char*)d_ws;
        float*  deg  = (float*)p;  p += n * sizeof(float);
        float*  dinv = (float*)p;  p += n * sizeof(float);
        float4* xs   = (float4*)p; p += n * sizeof(float4);
        float4* agg3 = (float4*)p; p += n * sizeof(float4);
        float*  gs   = (float*)p;  p += n * sizeof(float);
        float*  agg1 = (float*)p;  p += n * sizeof(float);
        int*    flag = (int*)p;

        k_detect<<<1, 64, 0, stream>>>((const int*)ei, flag);
        f_init_deg<<<gN, T, 0, stream>>>(deg, (int)n);
        f_deg<<<gE, T, 0, stream>>>(ei, flag, deg, E);
        f_dinv_xs<<<gN, T, 0, stream>>>(x, deg, dinv, xs, agg3, (int)n);
        f_edge1<<<gE, T, 0, stream>>>(ei, flag, xs, (float*)agg3, E);
        f_node1<<<gN, T, 0, stream>>>(dinv, agg3, W1, b1, W2, gs, agg1, (int)n);
        f_edge2<<<gE, T, 0, stream>>>(ei, flag, gs, agg1, E);
        f_final<<<gN, T, 0, stream>>>(dinv, agg1, b2, out, (int)n);
    }
}

// Round 4
// 151.101 us; speedup vs baseline: 1.1220x; 1.1220x over previous
//
#include <hip/hip_runtime.h>
#include <math.h>

// GCN 2-layer. R13: kernel-count fusion. R9-R12 showed totals are invariant
// (155-170us) under redistribution of edge work -> attack fixed costs:
// 8 dispatches + ~26MB partial write/read/combine round-trips.
// New pipeline (5 dispatches, NO partial arrays):
//   k_zf    : zero cursors + dtype flag
//   k_bin   : bucket edges, 1 LDS atomic/edge (R11 rank-register form)
//   k_degF  : one block per bucket: LDS count whole bucket -> dinv/xs epilogue
//   k_agg1FU: one block per bucket: u64 packed LDS accumulate whole bucket
//             -> decode + MLP epilogue -> gs  (same fixed-point math as R9;
//             full-bucket sum fits 21-bit fields: maxdeg*11800 < 2^21)
//   k_agg2FU: one block per bucket: f32 LDS accumulate -> sigmoid -> out
// Predict 156 -> ~120-135us. If >=150, launch overhead refuted -> go
// cooperative mega-kernel next.

#define NPB 256        // nodes per bucket (power of 2)
#define SHIFT 8        // log2(NPB)
#define NB_MAX 512     // max buckets supported by LDS arrays in k_bin
#define T1 512         // threads per block in k_bin
#define EPT 16         // edges staged per thread in k_bin (tile = 8192 edges)
#define T2 512         // threads per block in fused bucket kernels

#define FSCALE 1024.0f     // fixed-point scale (2^10)
#define FBIAS  8192        // per-addend bias (2^13)
#define FMASK  0x1FFFFFu   // 21-bit field mask

static __device__ __forceinline__ long long load_idx(const void* edges, long long pos, int is64) {
    if (is64) return ((const long long*)edges)[pos];
    return (long long)((const int*)edges)[pos];
}

static __device__ __forceinline__ unsigned long long pack3(float x, float y, float z) {
    unsigned long long e0 = (unsigned)(__float2int_rn(x * FSCALE) + FBIAS);
    unsigned long long e1 = (unsigned)(__float2int_rn(y * FSCALE) + FBIAS);
    unsigned long long e2 = (unsigned)(__float2int_rn(z * FSCALE) + FBIAS);
    return e0 | (e1 << 21) | (e2 << 42);
}

// zero cursors + dtype-detect flag (merged)
__global__ void k_zf(int* cursor, int nb, const int* e32, int* flag) {
    int i = blockIdx.x * blockDim.x + threadIdx.x;
    if (i < nb) cursor[i] = 0;
    if (i == 0) {
        int is64 = 1;
        for (int k = 0; k < 16; ++k)
            if (e32[2 * k + 1] != 0) { is64 = 0; break; }
        *flag = is64;
    }
}

// Register-staged binning: ONE pass over the edge list; 1 LDS atomic/edge
// (the histogram atomic's return value doubles as the placement rank).
__global__ void k_bin(const void* edges, const int* __restrict__ flag,
                      int* __restrict__ cursor, unsigned int* __restrict__ bin,
                      long long E, int nb, int cap) {
    __shared__ int hist[NB_MAX];
    __shared__ int base[NB_MAX];
    const int tid = threadIdx.x;
    for (int b = tid; b < nb; b += T1) hist[b] = 0;
    __syncthreads();

    const int is64 = *flag;
    const long long start = (long long)blockIdx.x * ((long long)T1 * EPT);
    unsigned es[EPT], ed[EPT];
    int rank[EPT];

    if (is64) {
        const long long* e64 = (const long long*)edges;
#pragma unroll
        for (int j = 0; j < EPT; ++j) {
            long long e = start + j * T1 + tid;
            if (e < E) { es[j] = (unsigned)e64[e]; ed[j] = (unsigned)e64[E + e]; }
            else ed[j] = 0xFFFFFFFFu;
        }
    } else {
        const int* e32 = (const int*)edges;
#pragma unroll
        for (int j = 0; j < EPT; ++j) {
            long long e = start + j * T1 + tid;
            if (e < E) { es[j] = (unsigned)e32[e]; ed[j] = (unsigned)e32[E + e]; }
            else ed[j] = 0xFFFFFFFFu;
        }
    }

#pragma unroll
    for (int j = 0; j < EPT; ++j)
        if (ed[j] != 0xFFFFFFFFu)
            rank[j] = atomicAdd(&hist[ed[j] >> SHIFT], 1);
    __syncthreads();

    for (int b = tid; b < nb; b += T1) {
        int h = hist[b];
        base[b] = h ? atomicAdd(&cursor[b], h) : 0;
    }
    __syncthreads();

#pragma unroll
    for (int j = 0; j < EPT; ++j) {
        if (ed[j] == 0xFFFFFFFFu) continue;
        int bk = (int)(ed[j] >> SHIFT);
        int off = base[bk] + rank[j];
        if (off < cap)
            bin[(long long)bk * cap + off] = ((ed[j] & (NPB - 1)) << 17) | es[j];
    }
}

// ---- fused degree: one block per bucket; LDS count + dinv/xs epilogue ----
__global__ void k_degF(const unsigned int* __restrict__ bin, const int* __restrict__ cursor,
                       const float* __restrict__ x, float* __restrict__ dinv,
                       float4* __restrict__ xs, int cap, int n) {
    __shared__ int dcnt[NPB];
    const int tid = threadIdx.x;
    if (tid < NPB) dcnt[tid] = 0;
    __syncthreads();
    const int bk = blockIdx.x;
    const int cnt = min(cursor[bk], cap);
    const unsigned int* bp = bin + (long long)bk * cap;
    const int nvec = cnt >> 2;
    const uint4* bp4 = (const uint4*)bp;
    for (int v = tid; v < nvec; v += T2) {
        uint4 q = bp4[v];
        atomicAdd(&dcnt[q.x >> 17], 1);
        atomicAdd(&dcnt[q.y >> 17], 1);
        atomicAdd(&dcnt[q.z >> 17], 1);
        atomicAdd(&dcnt[q.w >> 17], 1);
    }
    for (int k = (nvec << 2) + tid; k < cnt; k += T2)
        atomicAdd(&dcnt[bp[k] >> 17], 1);
    __syncthreads();
    if (tid < NPB) {
        const int i = bk * NPB + tid;
        if (i < n) {
            int degE = dcnt[tid];
            float di = rsqrtf((float)degE + 1.0f);
            dinv[i] = di;
            xs[i] = make_float4(x[3 * i] * di, x[3 * i + 1] * di, x[3 * i + 2] * di, (float)degE);
        }
    }
}

// ---- fused layer 1: one block per bucket; u64 packed LDS accumulate +
// decode/MLP epilogue. Full-bucket sums stay in 21-bit fields. ----
__global__ void k_agg1FU(const unsigned int* __restrict__ bin, const int* __restrict__ cursor,
                         const float4* __restrict__ xs, const float* __restrict__ dinv,
                         const float* __restrict__ W1, const float* __restrict__ b1,
                         const float* __restrict__ W2, float* __restrict__ gs,
                         int cap, int n) {
    __shared__ unsigned long long acc[NPB];
    const int tid = threadIdx.x;
    if (tid < NPB) acc[tid] = 0ull;
    __syncthreads();
    const int bk = blockIdx.x;
    const int cnt = min(cursor[bk], cap);
    const unsigned int* bp = bin + (long long)bk * cap;
    const int nvec = cnt >> 2;
    const uint4* bp4 = (const uint4*)bp;
    for (int v = tid; v < nvec; v += T2) {
        uint4 q = bp4[v];
        float4 v0 = xs[q.x & 0x1FFFFu];
        float4 v1 = xs[q.y & 0x1FFFFu];
        float4 v2 = xs[q.z & 0x1FFFFu];
        float4 v3 = xs[q.w & 0x1FFFFu];
        atomicAdd(&acc[q.x >> 17], pack3(v0.x, v0.y, v0.z));
        atomicAdd(&acc[q.y >> 17], pack3(v1.x, v1.y, v1.z));
        atomicAdd(&acc[q.z >> 17], pack3(v2.x, v2.y, v2.z));
        atomicAdd(&acc[q.w >> 17], pack3(v3.x, v3.y, v3.z));
    }
    for (int k = (nvec << 2) + tid; k < cnt; k += T2) {
        unsigned p = bp[k];
        float4 v = xs[p & 0x1FFFFu];
        atomicAdd(&acc[p >> 17], pack3(v.x, v.y, v.z));
    }
    __syncthreads();
    if (tid < NPB) {
        const int i = bk * NPB + tid;
        if (i < n) {
            unsigned long long p = acc[tid];
            int f0 = (int)(p & FMASK);
            int f1 = (int)((p >> 21) & FMASK);
            int f2 = (int)((p >> 42) & FMASK);
            float4 self = xs[i];
            int degE = (int)self.w;
            const float inv = 1.0f / FSCALE;
            float a0 = (float)(f0 - FBIAS * degE) * inv + self.x;
            float a1 = (float)(f1 - FBIAS * degE) * inv + self.y;
            float a2 = (float)(f2 - FBIAS * degE) * inv + self.z;
            float di = dinv[i];
            a0 *= di; a1 *= di; a2 *= di;
            float g = 0.0f;
#pragma unroll
            for (int c = 0; c < 16; ++c) {   // W1 [3,16] row-major
                float h = fmaf(a0, W1[c], fmaf(a1, W1[16 + c], fmaf(a2, W1[32 + c], b1[c])));
                h = fmaxf(h, 0.0f);
                g = fmaf(h, W2[c], g);
            }
            gs[i] = g * di;   // pre-scaled by dinv for layer-2 src side
        }
    }
}

// ---- fused layer 2: one block per bucket; f32 LDS accumulate + sigmoid ----
__global__ void k_agg2FU(const unsigned int* __restrict__ bin, const int* __restrict__ cursor,
                         const float* __restrict__ gs, const float* __restrict__ dinv,
                         const float* __restrict__ b2, float* __restrict__ out,
                         int cap, int n) {
    __shared__ float facc[NPB];
    const int tid = threadIdx.x;
    if (tid < NPB) facc[tid] = 0.0f;
    __syncthreads();
    const int bk = blockIdx.x;
    const int cnt = min(cursor[bk], cap);
    const unsigned int* bp = bin + (long long)bk * cap;
    const int nvec = cnt >> 2;
    const uint4* bp4 = (const uint4*)bp;
    for (int v = tid; v < nvec; v += T2) {
        uint4 q = bp4[v];
        float g0 = gs[q.x & 0x1FFFFu];
        float g1 = gs[q.y & 0x1FFFFu];
        float g2 = gs[q.z & 0x1FFFFu];
        float g3 = gs[q.w & 0x1FFFFu];
        atomicAdd(&facc[q.x >> 17], g0);
        atomicAdd(&facc[q.y >> 17], g1);
        atomicAdd(&facc[q.z >> 17], g2);
        atomicAdd(&facc[q.w >> 17], g3);
    }
    for (int k = (nvec << 2) + tid; k < cnt; k += T2)
        atomicAdd(&facc[bp[k] >> 17], gs[bp[k] & 0x1FFFFu]);
    __syncthreads();
    if (tid < NPB) {
        const int i = bk * NPB + tid;
        if (i < n) {
            float z = dinv[i] * (facc[tid] + gs[i]) + b2[0];
            out[i] = 1.0f / (1.0f + expf(-z));
        }
    }
}

// ---------------- R1 fallback (small ws) ----------------
__global__ void k_detect(const int* e32, int* flag) {
    if (blockIdx.x == 0 && threadIdx.x == 0) {
        int is64 = 1;
        for (int k = 0; k < 16; ++k)
            if (e32[2 * k + 1] != 0) { is64 = 0; break; }
        *flag = is64;
    }
}
__global__ void f_init_deg(float* deg, int n) {
    int i = blockIdx.x * blockDim.x + threadIdx.x;
    if (i < n) deg[i] = 1.0f;
}
__global__ void f_deg(const void* edges, const int* flag, float* deg, long long E) {
    int is64 = *flag;
    long long e = (long long)blockIdx.x * blockDim.x + threadIdx.x;
    if (e < E) atomicAdd(&deg[load_idx(edges, E + e, is64)], 1.0f);
}
__global__ void f_dinv_xs(const float* x, const float* deg, float* dinv, float4* xs,
                          float4* agg3, int n) {
    int i = blockIdx.x * blockDim.x + threadIdx.x;
    if (i < n) {
        float di = rsqrtf(deg[i]);
        dinv[i] = di;
        float4 v = make_float4(x[3 * i] * di, x[3 * i + 1] * di, x[3 * i + 2] * di, 0.0f);
        xs[i] = v; agg3[i] = v;
    }
}
__global__ void f_edge1(const void* edges, const int* flag, const float4* xs,
                        float* agg3, long long E) {
    int is64 = *flag;
    long long e = (long long)blockIdx.x * blockDim.x + threadIdx.x;
    if (e < E) {
        long long s = load_idx(edges, e, is64);
        long long d = load_idx(edges, E + e, is64);
        float4 v = xs[s];
        atomicAdd(&agg3[4 * d + 0], v.x);
        atomicAdd(&agg3[4 * d + 1], v.y);
        atomicAdd(&agg3[4 * d + 2], v.z);
    }
}
__global__ void f_node1(const float* dinv, const float4* agg3, const float* W1,
                        const float* b1, const float* W2, float* gs, float* agg1, int n) {
    int i = blockIdx.x * blockDim.x + threadIdx.x;
    if (i < n) {
        float di = dinv[i];
        float4 a = agg3[i];
        float a0 = a.x * di, a1 = a.y * di, a2 = a.z * di;
        float g = 0.0f;
#pragma unroll
        for (int k = 0; k < 16; ++k) {
            float h = fmaf(a0, W1[k], fmaf(a1, W1[16 + k], fmaf(a2, W1[32 + k], b1[k])));
            h = fmaxf(h, 0.0f);
            g = fmaf(h, W2[k], g);
        }
        float v = g * di;
        gs[i] = v; agg1[i] = v;
    }
}
__global__ void f_edge2(const void* edges, const int* flag, const float* gs,
                        float* agg1, long long E) {
    int is64 = *flag;
    long long e = (long long)blockIdx.x * blockDim.x + threadIdx.x;
    if (e < E) atomicAdd(&agg1[load_idx(edges, E + e, is64)], gs[load_idx(edges, e, is64)]);
}
__global__ void f_final(const float* dinv, const float* agg1, const float* b2,
                        float* out, int n) {
    int i = blockIdx.x * blockDim.x + threadIdx.x;
    if (i < n) {
        float z = dinv[i] * agg1[i] + b2[0];
        out[i] = 1.0f / (1.0f + expf(-z));
    }
}

extern "C" void kernel_launch(void* const* d_in, const int* in_sizes, int n_in,
                              void* d_out, int out_size, void* d_ws, size_t ws_size,
                              hipStream_t stream) {
    const float* x  = (const float*)d_in[0];
    const void*  ei = d_in[1];
    const float* W1 = (const float*)d_in[2];
    const float* b1 = (const float*)d_in[3];
    const float* W2 = (const float*)d_in[4];
    const float* b2 = (const float*)d_in[5];
    float* out = (float*)d_out;

    const long long n = in_sizes[0] / 3;   // 100000
    const long long E = in_sizes[1] / 2;   // 3200000

    const int T = 256;
    const int gN = (int)((n + T - 1) / T);
    const int gE = (int)((E + T - 1) / T);

    const int nb = (int)((n + NPB - 1) / NPB);                       // 391
    long long capll = (E / nb) + (E / nb) / 8 + 256;                 // mean + ~11 sigma
    const int cap = (int)((capll + 63) / 64 * 64);

    size_t need = n * sizeof(float4)                                 // xs
                + (size_t)nb * cap * sizeof(int)                     // bin
                + 2 * n * sizeof(float)                              // dinv, gs
                + nb * sizeof(int) + 128;                            // cursor, flag

    if (nb <= NB_MAX && n <= (1 << 17) && ws_size >= need) {
        char* p = (char*)d_ws;
        float4* xs   = (float4*)p;            p += n * sizeof(float4);
        unsigned int* bin = (unsigned int*)p; p += (size_t)nb * cap * sizeof(int);
        float* dinv  = (float*)p;             p += n * sizeof(float);
        float* gs    = (float*)p;             p += n * sizeof(float);
        int*   cursor = (int*)p;              p += nb * sizeof(int);
        int*   flag  = (int*)p;

        const long long per_blk = (long long)T1 * EPT;               // 8192 edges/block
        const int gB = (int)((E + per_blk - 1) / per_blk);           // 391

        k_zf<<<(nb + T - 1) / T, T, 0, stream>>>(cursor, nb, (const int*)ei, flag);
        k_bin<<<gB, T1, 0, stream>>>(ei, flag, cursor, bin, E, nb, cap);
        k_degF<<<nb, T2, 0, stream>>>(bin, cursor, x, dinv, xs, cap, (int)n);
        k_agg1FU<<<nb, T2, 0, stream>>>(bin, cursor, xs, dinv, W1, b1, W2, gs, cap, (int)n);
        k_agg2FU<<<nb, T2, 0, stream>>>(bin, cursor, gs, dinv, b2, out, cap, (int)n);
    } else {
        // R1 proven atomic pipeline
        char* p = (char*)d_ws;
        float*  deg  = (float*)p;  p += n * sizeof(float);
        float*  dinv = (float*)p;  p += n * sizeof(float);
        float4* xs   = (float4*)p; p += n * sizeof(float4);
        float4* agg3 = (float4*)p; p += n * sizeof(float4);
        float*  gs   = (float*)p;  p += n * sizeof(float);
        float*  agg1 = (float*)p;  p += n * sizeof(float);
        int*    flag = (int*)p;

        k_detect<<<1, 64, 0, stream>>>((const int*)ei, flag);
        f_init_deg<<<gN, T, 0, stream>>>(deg, (int)n);
        f_deg<<<gE, T, 0, stream>>>(ei, flag, deg, E);
        f_dinv_xs<<<gN, T, 0, stream>>>(x, deg, dinv, xs, agg3, (int)n);
        f_edge1<<<gE, T, 0, stream>>>(ei, flag, xs, (float*)agg3, E);
        f_node1<<<gN, T, 0, stream>>>(dinv, agg3, W1, b1, W2, gs, agg1, (int)n);
        f_edge2<<<gE, T, 0, stream>>>(ei, flag, gs, agg1, E);
        f_final<<<gN, T, 0, stream>>>(dinv, agg1, b2, out, (int)n);
    }
}